// Round 3
// baseline (10407.784 us; speedup 1.0000x reference)
//
#include <hip/hip_runtime.h>
#include <hip/hip_bf16.h>
#include <math.h>

#define EPSBN 1e-5f

// ---------------- workspace layout (BYTE offsets), peak 55,685,376 B ~= 53.1 MiB ----
// W    f32 @ 0          : 683,072 floats (2,732,288 B)
// SC   f32 @ 2,732,288  : 32*4096       (524,288 B)
// BF   f32 @ 3,256,576  : 32*4*4096     (2,097,152 B)
// A2C  f32 @ 5,353,728  : 8*64*128*128  (33,554,432 B)   [per-chunk]
// A3C  f32 @ 38,908,160 : 8*128*64*64   (16,777,216 B)   [per-chunk]
//
// W region internal layout (float offsets):
//  wT1 @0 (864) | b1f @864 (32) | wT2 @896 (18432) | b2f @19328 (64)
//  wT3 @19392 (73728) | b3f @93120 (128) | dwT1 @93248 (294912) | bwT1 @388160 (294912)

// ---------------- prep: BN-fold + weight transpose ----------------
__global__ __launch_bounds__(256) void prep_k(
    const float* __restrict__ w1, const float* __restrict__ b1, const float* __restrict__ g1,
    const float* __restrict__ be1, const float* __restrict__ m1, const float* __restrict__ v1,
    const float* __restrict__ w2, const float* __restrict__ b2, const float* __restrict__ g2,
    const float* __restrict__ be2, const float* __restrict__ m2, const float* __restrict__ v2,
    const float* __restrict__ w3, const float* __restrict__ b3, const float* __restrict__ g3,
    const float* __restrict__ be3, const float* __restrict__ m3, const float* __restrict__ v3,
    const float* __restrict__ dw1, const float* __restrict__ bw1, float* __restrict__ W)
{
    int i = blockIdx.x * 256 + threadIdx.x;
    if (i < 864) {                                   // wT1[(kk*3+ci)*32+co]
        int co = i & 31; int r = i >> 5; int ci = r % 3; int kk = r / 3;
        float A = g1[co] * rsqrtf(v1[co] + EPSBN);
        W[i] = w1[(co*3 + ci)*9 + kk] * A;
    } else if (i < 896) {                            // b1 fold
        int co = i - 864;
        float A = g1[co] * rsqrtf(v1[co] + EPSBN);
        W[i] = (b1[co] - m1[co]) * A + be1[co];
    } else if (i < 19328) {                          // wT2[(kk*32+ci)*64+co]
        int j = i - 896; int co = j & 63; int r = j >> 6; int ci = r & 31; int kk = r >> 5;
        float A = g2[co] * rsqrtf(v2[co] + EPSBN);
        W[i] = w2[(co*32 + ci)*9 + kk] * A;
    } else if (i < 19392) {                          // b2 fold
        int co = i - 19328;
        float A = g2[co] * rsqrtf(v2[co] + EPSBN);
        W[i] = (b2[co] - m2[co]) * A + be2[co];
    } else if (i < 93120) {                          // wT3[(kk*64+ci)*128+co]
        int j = i - 19392; int co = j & 127; int r = j >> 7; int ci = r & 63; int kk = r >> 6;
        float A = g3[co] * rsqrtf(v3[co] + EPSBN);
        W[i] = w3[(co*64 + ci)*9 + kk] * A;
    } else if (i < 93248) {                          // b3 fold
        int co = i - 93120;
        float A = g3[co] * rsqrtf(v3[co] + EPSBN);
        W[i] = (b3[co] - m3[co]) * A + be3[co];
    } else if (i < 388160) {                         // dwT1[(kk*128+ci)*256+co]
        int j = i - 93248; int co = j & 255; int r = j >> 8; int ci = r & 127; int kk = r >> 7;
        W[i] = dw1[(co*128 + ci)*9 + kk];
    } else if (i < 683072) {                         // bwT1[(kk*128+ci)*256+co]
        int j = i - 388160; int co = j & 255; int r = j >> 8; int ci = r & 127; int kk = r >> 7;
        W[i] = bw1[(co*128 + ci)*9 + kk];
    }
}

// ---------------- fused conv1(3->32,s2)+BN+ReLU -> conv2(32->64,s2)+BN+ReLU ----------
// block: one 16x16 out2 tile, all 64 couts, one image. conv1 halo (33x33) staged in
// LDS in 2 groups of 16 conv1-couts, column-interleaved for stride-2-friendly reads.
__global__ __launch_bounds__(256) void conv12_k(
    const float* __restrict__ x, const float* __restrict__ W,
    float* __restrict__ out2, int b0)
{
    __shared__ float s1[17424];                     // 16 * 33 * 33 floats
    const int tid  = threadIdx.x;
    const int lane = tid & 63;
    const int wv   = tid >> 6;
    const int cob  = wv * 16;

    const int bl   = blockIdx.x >> 6;               // chunk-local image 0..7
    const int tile = blockIdx.x & 63;
    const int OY = (tile >> 3) * 16, OX = (tile & 7) * 16;
    const int base1y = 2*OY - 1, base1x = 2*OX - 1;

    const float* xb = x + (size_t)(b0 + bl) * 3 * 262144;

    float acc[4][16];
    #pragma unroll
    for (int j = 0; j < 4; j++)
        #pragma unroll
        for (int c = 0; c < 16; c++) acc[j][c] = 0.f;

    int px[4], py[4];
    #pragma unroll
    for (int j = 0; j < 4; j++) { int p = lane + 64*j; px[j] = p & 15; py[j] = p >> 4; }

    for (int g = 0; g < 2; g++) {
        if (g) __syncthreads();
        // ---- conv1 phase: couts [16g,16g+16) over 33x33 halo ----
        for (int idx = tid; idx < 1089; idx += 256) {
            int row = idx / 33;
            int lx  = idx - row*33;
            int y1 = base1y + row;
            int x1 = base1x + lx;
            float c1[16];
            #pragma unroll
            for (int c = 0; c < 16; c++) c1[c] = 0.f;
            if (((unsigned)y1 < 256u) && ((unsigned)x1 < 256u)) {
                #pragma unroll
                for (int ky = 0; ky < 3; ky++) {
                    int xy = 2*y1 + ky - 1;
                    if ((unsigned)xy < 512u) {
                        #pragma unroll
                        for (int kx = 0; kx < 3; kx++) {
                            int xx = 2*x1 + kx - 1;
                            if ((unsigned)xx < 512u) {
                                int kk = ky*3 + kx;
                                #pragma unroll
                                for (int ci = 0; ci < 3; ci++) {
                                    float v = xb[(size_t)ci*262144 + xy*512 + xx];
                                    const float4* w4 = (const float4*)(W + (kk*3+ci)*32 + 16*g);
                                    float4 wa = w4[0], wb = w4[1], wc = w4[2], wd = w4[3];
                                    c1[0]  = fmaf(v, wa.x, c1[0]);  c1[1]  = fmaf(v, wa.y, c1[1]);
                                    c1[2]  = fmaf(v, wa.z, c1[2]);  c1[3]  = fmaf(v, wa.w, c1[3]);
                                    c1[4]  = fmaf(v, wb.x, c1[4]);  c1[5]  = fmaf(v, wb.y, c1[5]);
                                    c1[6]  = fmaf(v, wb.z, c1[6]);  c1[7]  = fmaf(v, wb.w, c1[7]);
                                    c1[8]  = fmaf(v, wc.x, c1[8]);  c1[9]  = fmaf(v, wc.y, c1[9]);
                                    c1[10] = fmaf(v, wc.z, c1[10]); c1[11] = fmaf(v, wc.w, c1[11]);
                                    c1[12] = fmaf(v, wd.x, c1[12]); c1[13] = fmaf(v, wd.y, c1[13]);
                                    c1[14] = fmaf(v, wd.z, c1[14]); c1[15] = fmaf(v, wd.w, c1[15]);
                                }
                            }
                        }
                    }
                }
                #pragma unroll
                for (int c = 0; c < 16; c++)
                    c1[c] = fmaxf(c1[c] + W[864 + 16*g + c], 0.f);
            }
            int xi = (lx & 1) * 17 + (lx >> 1);     // column interleave
            #pragma unroll
            for (int c = 0; c < 16; c++)
                s1[c*1089 + row*33 + xi] = c1[c];
        }
        __syncthreads();
        // ---- conv2 accumulate over ci in [16g,16g+16) ----
        for (int ky = 0; ky < 3; ky++) {
            for (int kx = 0; kx < 3; kx++) {
                int kk = ky*3 + kx;
                int xbase = (kx & 1) * 17 + (kx >> 1);
                #pragma unroll 2
                for (int ci = 0; ci < 16; ci++) {
                    int cig = 16*g + ci;
                    const float4* w4 = (const float4*)(W + 896 + (kk*32 + cig)*64 + cob);
                    float4 wa = w4[0], wb = w4[1], wc = w4[2], wd = w4[3];
                    #pragma unroll
                    for (int j = 0; j < 4; j++) {
                        float v = s1[ci*1089 + (2*py[j] + ky)*33 + xbase + px[j]];
                        acc[j][0]  = fmaf(v, wa.x, acc[j][0]);  acc[j][1]  = fmaf(v, wa.y, acc[j][1]);
                        acc[j][2]  = fmaf(v, wa.z, acc[j][2]);  acc[j][3]  = fmaf(v, wa.w, acc[j][3]);
                        acc[j][4]  = fmaf(v, wb.x, acc[j][4]);  acc[j][5]  = fmaf(v, wb.y, acc[j][5]);
                        acc[j][6]  = fmaf(v, wb.z, acc[j][6]);  acc[j][7]  = fmaf(v, wb.w, acc[j][7]);
                        acc[j][8]  = fmaf(v, wc.x, acc[j][8]);  acc[j][9]  = fmaf(v, wc.y, acc[j][9]);
                        acc[j][10] = fmaf(v, wc.z, acc[j][10]); acc[j][11] = fmaf(v, wc.w, acc[j][11]);
                        acc[j][12] = fmaf(v, wd.x, acc[j][12]); acc[j][13] = fmaf(v, wd.y, acc[j][13]);
                        acc[j][14] = fmaf(v, wd.z, acc[j][14]); acc[j][15] = fmaf(v, wd.w, acc[j][15]);
                    }
                }
            }
        }
    }
    // epilogue: bias + relu -> f32
    #pragma unroll
    for (int c = 0; c < 16; c++) {
        float bs = W[19328 + cob + c];
        #pragma unroll
        for (int j = 0; j < 4; j++) {
            float rv = fmaxf(acc[j][c] + bs, 0.f);
            out2[((size_t)(bl*64 + cob + c)*128 + (OY + py[j]))*128 + OX + px[j]] = rv;
        }
    }
}

// ---------------- conv3: 64->128, k3 s2, 128->64, f32, fused BN+ReLU (chunk-local) --
__global__ __launch_bounds__(256) void conv3_k(
    const float* __restrict__ in, const float* __restrict__ wT,
    const float* __restrict__ bias, float* __restrict__ out)
{
    const int lane = threadIdx.x & 63;
    const int wv   = threadIdx.x >> 6;
    const int cob  = blockIdx.y * 64 + wv * 16;
    const int pix0 = blockIdx.x * 256;              // chunk-local: 8 img * 4096 px
    const int bl   = pix0 >> 12;
    const int off0 = pix0 & 4095;

    float acc[4][16];
    #pragma unroll
    for (int j = 0; j < 4; j++)
        #pragma unroll
        for (int c = 0; c < 16; c++) acc[j][c] = 0.f;

    int oy[4], ox[4];
    #pragma unroll
    for (int j = 0; j < 4; j++) {
        int off = off0 + lane + 64*j;
        ox[j] = off & 63;
        oy[j] = off >> 6;
    }
    const float* inb = in + (size_t)bl * 64 * 16384;

    for (int ky = 0; ky < 3; ky++) {
        for (int kx = 0; kx < 3; kx++) {
            int addr[4]; float mk[4];
            #pragma unroll
            for (int j = 0; j < 4; j++) {
                int iy = oy[j]*2 + ky - 1;
                int ix = ox[j]*2 + kx - 1;
                bool v = ((unsigned)iy < 128u) && ((unsigned)ix < 128u);
                addr[j] = v ? iy*128 + ix : 0;
                mk[j]   = v ? 1.f : 0.f;
            }
            const float* wp = wT + (size_t)((ky*3 + kx)*64)*128 + cob;
            #pragma unroll 2
            for (int ci = 0; ci < 64; ci++) {
                float v0 = inb[(size_t)ci*16384 + addr[0]] * mk[0];
                float v1 = inb[(size_t)ci*16384 + addr[1]] * mk[1];
                float v2 = inb[(size_t)ci*16384 + addr[2]] * mk[2];
                float v3 = inb[(size_t)ci*16384 + addr[3]] * mk[3];
                const float4* w4 = (const float4*)(wp + (size_t)ci*128);
                float4 wa = w4[0], wb = w4[1], wc = w4[2], wd = w4[3];
                float vv[4] = {v0, v1, v2, v3};
                #pragma unroll
                for (int j = 0; j < 4; j++) {
                    float v = vv[j];
                    acc[j][0]  = fmaf(v, wa.x, acc[j][0]);  acc[j][1]  = fmaf(v, wa.y, acc[j][1]);
                    acc[j][2]  = fmaf(v, wa.z, acc[j][2]);  acc[j][3]  = fmaf(v, wa.w, acc[j][3]);
                    acc[j][4]  = fmaf(v, wb.x, acc[j][4]);  acc[j][5]  = fmaf(v, wb.y, acc[j][5]);
                    acc[j][6]  = fmaf(v, wb.z, acc[j][6]);  acc[j][7]  = fmaf(v, wb.w, acc[j][7]);
                    acc[j][8]  = fmaf(v, wc.x, acc[j][8]);  acc[j][9]  = fmaf(v, wc.y, acc[j][9]);
                    acc[j][10] = fmaf(v, wc.z, acc[j][10]); acc[j][11] = fmaf(v, wc.w, acc[j][11]);
                    acc[j][12] = fmaf(v, wd.x, acc[j][12]); acc[j][13] = fmaf(v, wd.y, acc[j][13]);
                    acc[j][14] = fmaf(v, wd.z, acc[j][14]); acc[j][15] = fmaf(v, wd.w, acc[j][15]);
                }
            }
        }
    }
    #pragma unroll
    for (int c = 0; c < 16; c++) {
        float bs = bias[cob + c];
        #pragma unroll
        for (int j = 0; j < 4; j++) {
            float rv = fmaxf(acc[j][c] + bs, 0.f);
            out[((size_t)(bl*128 + cob + c))*4096 + off0 + lane + 64*j] = rv;
        }
    }
}

// ---------------- fused head: conv3x3(128->256)+ReLU + 1x1(256->NOUT), f32 ----------
// 512 threads = 8 waves; wave w -> cout slices {16w, 128+16w}; thread: 1 px x 32 co.
// Tile: 1 row x 64 cols. Grid per chunk: 8 img * 64 rows = 512 blocks.
template<int NOUT>
__global__ __launch_bounds__(512) void head_k(
    const float* __restrict__ in, const float* __restrict__ wT,
    const float* __restrict__ b1, const float* __restrict__ w2,
    const float* __restrict__ b2, float* __restrict__ outp, int b0)
{
    __shared__ float red[512];                      // [8 waves][64 px]
    const int tid  = threadIdx.x;
    const int lane = tid & 63;
    const int wv   = tid >> 6;                      // 0..7
    const int cg0  = wv * 16;                       // slice A
    const int cg1  = 128 + wv * 16;                 // slice B
    const int bl   = blockIdx.x >> 6;               // chunk-local image
    const int Y    = blockIdx.x & 63;               // output row

    float acc0[16], acc1[16];
    #pragma unroll
    for (int c = 0; c < 16; c++) { acc0[c] = 0.f; acc1[c] = 0.f; }

    const float* inb = in + (size_t)bl * 128 * 4096;

    for (int ky = 0; ky < 3; ky++) {
        int r = Y + ky - 1;
        bool vr = (unsigned)r < 64u;
        for (int kx = 0; kx < 3; kx++) {
            int col = lane + kx - 1;
            bool vv = vr && ((unsigned)col < 64u);
            int ad  = vv ? r*64 + col : 0;
            float mk = vv ? 1.f : 0.f;
            const float* wp = wT + (size_t)((ky*3 + kx)*128)*256 + cg0;
            #pragma unroll 2
            for (int ci = 0; ci < 128; ci++) {
                float v = inb[(size_t)ci*4096 + ad] * mk;
                const float4* w4a = (const float4*)(wp + (size_t)ci*256);
                const float4* w4b = (const float4*)(wp + (size_t)ci*256 + 128);
                float4 a0 = w4a[0], a1 = w4a[1], a2 = w4a[2], a3 = w4a[3];
                float4 e0 = w4b[0], e1 = w4b[1], e2 = w4b[2], e3 = w4b[3];
                acc0[0]  = fmaf(v, a0.x, acc0[0]);  acc0[1]  = fmaf(v, a0.y, acc0[1]);
                acc0[2]  = fmaf(v, a0.z, acc0[2]);  acc0[3]  = fmaf(v, a0.w, acc0[3]);
                acc0[4]  = fmaf(v, a1.x, acc0[4]);  acc0[5]  = fmaf(v, a1.y, acc0[5]);
                acc0[6]  = fmaf(v, a1.z, acc0[6]);  acc0[7]  = fmaf(v, a1.w, acc0[7]);
                acc0[8]  = fmaf(v, a2.x, acc0[8]);  acc0[9]  = fmaf(v, a2.y, acc0[9]);
                acc0[10] = fmaf(v, a2.z, acc0[10]); acc0[11] = fmaf(v, a2.w, acc0[11]);
                acc0[12] = fmaf(v, a3.x, acc0[12]); acc0[13] = fmaf(v, a3.y, acc0[13]);
                acc0[14] = fmaf(v, a3.z, acc0[14]); acc0[15] = fmaf(v, a3.w, acc0[15]);
                acc1[0]  = fmaf(v, e0.x, acc1[0]);  acc1[1]  = fmaf(v, e0.y, acc1[1]);
                acc1[2]  = fmaf(v, e0.z, acc1[2]);  acc1[3]  = fmaf(v, e0.w, acc1[3]);
                acc1[4]  = fmaf(v, e1.x, acc1[4]);  acc1[5]  = fmaf(v, e1.y, acc1[5]);
                acc1[6]  = fmaf(v, e1.z, acc1[6]);  acc1[7]  = fmaf(v, e1.w, acc1[7]);
                acc1[8]  = fmaf(v, e2.x, acc1[8]);  acc1[9]  = fmaf(v, e2.y, acc1[9]);
                acc1[10] = fmaf(v, e2.z, acc1[10]); acc1[11] = fmaf(v, e2.w, acc1[11]);
                acc1[12] = fmaf(v, e3.x, acc1[12]); acc1[13] = fmaf(v, e3.y, acc1[13]);
                acc1[14] = fmaf(v, e3.z, acc1[14]); acc1[15] = fmaf(v, e3.w, acc1[15]);
            }
        }
    }
    // bias + relu (conv3x3 epilogue)
    #pragma unroll
    for (int c = 0; c < 16; c++) {
        acc0[c] = fmaxf(acc0[c] + b1[cg0 + c], 0.f);
        acc1[c] = fmaxf(acc1[c] + b1[cg1 + c], 0.f);
    }
    // 1x1 conv: per-wave partial dot over its 32 couts, LDS reduce over 8 waves
    for (int p = 0; p < NOUT; p++) {
        float part = 0.f;
        #pragma unroll
        for (int c = 0; c < 16; c++) {
            part = fmaf(acc0[c], w2[p*256 + cg0 + c], part);
            part = fmaf(acc1[c], w2[p*256 + cg1 + c], part);
        }
        red[wv*64 + lane] = part;
        __syncthreads();
        if (tid < 64) {
            float t = b2[p];
            #pragma unroll
            for (int ww = 0; ww < 8; ww++) t += red[ww*64 + tid];
            outp[((size_t)((b0 + bl)*NOUT + p))*4096 + Y*64 + tid] = t;  // raw logit
        }
        __syncthreads();
    }
}

// ---------------- top-8 per image + gather + sigmoid*512 + mask --------------------
__global__ __launch_bounds__(256) void topk_k(
    const float* __restrict__ scores, const float* __restrict__ bflat,
    float* __restrict__ outp)
{
    __shared__ float sv[4096];
    __shared__ float rv[256];
    __shared__ int   ri[256];
    __shared__ float kv[8];
    __shared__ int   kidx[8];
    int b = blockIdx.x, t = threadIdx.x;
    for (int i = t; i < 4096; i += 256) sv[i] = scores[b*4096 + i];
    __syncthreads();
    for (int k = 0; k < 8; k++) {
        float bv = -INFINITY; int bi = 0x7fffffff;
        for (int i = t; i < 4096; i += 256) {
            float v = sv[i];
            if (v > bv || (v == bv && i < bi)) { bv = v; bi = i; }
        }
        rv[t] = bv; ri[t] = bi;
        __syncthreads();
        for (int s = 128; s > 0; s >>= 1) {
            if (t < s) {
                float v2 = rv[t+s]; int i2 = ri[t+s];
                if (v2 > rv[t] || (v2 == rv[t] && i2 < ri[t])) { rv[t] = v2; ri[t] = i2; }
            }
            __syncthreads();
        }
        if (t == 0) { kv[k] = rv[0]; kidx[k] = ri[0]; sv[ri[0]] = -INFINITY; }
        __syncthreads();
    }
    if (t < 32) {
        int k = t >> 2, c = t & 3;
        int idx = kidx[k];
        float s  = 1.f / (1.f + expf(-kv[k]));
        float lg = bflat[((size_t)(b*4 + c))*4096 + idx];
        float box = 512.f / (1.f + expf(-lg));
        outp[(b*8 + k)*4 + c] = (s > 0.5f) ? box : 0.f;
    }
}

extern "C" void kernel_launch(void* const* d_in, const int* in_sizes, int n_in,
                              void* d_out, int out_size, void* d_ws, size_t ws_size,
                              hipStream_t stream)
{
    const float* x   = (const float*)d_in[0];
    const float* w1  = (const float*)d_in[1];
    const float* b1  = (const float*)d_in[2];
    const float* g1  = (const float*)d_in[3];
    const float* be1 = (const float*)d_in[4];
    const float* m1  = (const float*)d_in[5];
    const float* v1  = (const float*)d_in[6];
    const float* w2  = (const float*)d_in[7];
    const float* b2  = (const float*)d_in[8];
    const float* g2  = (const float*)d_in[9];
    const float* be2 = (const float*)d_in[10];
    const float* m2  = (const float*)d_in[11];
    const float* v2  = (const float*)d_in[12];
    const float* w3  = (const float*)d_in[13];
    const float* b3  = (const float*)d_in[14];
    const float* g3  = (const float*)d_in[15];
    const float* be3 = (const float*)d_in[16];
    const float* m3  = (const float*)d_in[17];
    const float* v3  = (const float*)d_in[18];
    const float* dw1 = (const float*)d_in[19];
    const float* db1 = (const float*)d_in[20];
    const float* dw2 = (const float*)d_in[21];
    const float* db2 = (const float*)d_in[22];
    const float* bw1 = (const float*)d_in[23];
    const float* bb1 = (const float*)d_in[24];
    const float* bw2 = (const float*)d_in[25];
    const float* bb2 = (const float*)d_in[26];

    char*  wsb = (char*)d_ws;
    float* W   = (float*)wsb;
    float* SC  = (float*)(wsb + 2732288);
    float* BF  = (float*)(wsb + 3256576);
    float* A2C = (float*)(wsb + 5353728);
    float* A3C = (float*)(wsb + 38908160);
    float* out = (float*)d_out;

    // prep: BN-fold + transpose (683,072 floats)
    prep_k<<<2669, 256, 0, stream>>>(w1,b1,g1,be1,m1,v1, w2,b2,g2,be2,m2,v2,
                                     w3,b3,g3,be3,m3,v3, dw1, bw1, W);
    // full pipeline in 4 chunks of 8 images (A2C, A3C reused per chunk)
    for (int c = 0; c < 4; c++) {
        conv12_k<<<512, 256, 0, stream>>>(x, W, A2C, c*8);
        conv3_k<<<dim3(128, 2), 256, 0, stream>>>(A2C, W + 19392, W + 93120, A3C);
        head_k<1><<<512, 512, 0, stream>>>(A3C, W + 93248,  db1, dw2, db2, SC, c*8);
        head_k<4><<<512, 512, 0, stream>>>(A3C, W + 388160, bb1, bw2, bb2, BF, c*8);
    }
    // fused top-k + gather + sigmoid + mask
    topk_k<<<32, 256, 0, stream>>>(SC, BF, out);
}

// Round 4
// 2317.430 us; speedup vs baseline: 4.4911x; 4.4911x over previous
//
#include <hip/hip_runtime.h>
#include <math.h>

#define EPSBN 1e-5f

typedef __attribute__((ext_vector_type(4))) float f32x4;
typedef __attribute__((ext_vector_type(8))) short s16x8;

__device__ __forceinline__ unsigned short f2bf(float f) {
    unsigned u = __builtin_bit_cast(unsigned, f);
    u = (u + 0x7fffu + ((u >> 16) & 1u)) >> 16;
    return (unsigned short)u;
}
__device__ __forceinline__ float bf2f(unsigned short s) {
    unsigned u = ((unsigned)s) << 16;
    return __builtin_bit_cast(float, u);
}

// ---------------- workspace layout (BYTE offsets), peak 55,685,376 B ----------------
// W    f32 @ 0          : 93,248 floats (372,992 B)   backbone folded weights
// WF   bf16 @ 372,992   : 1,179,648 shorts (2,359,296 B) head weights, frag-ordered hi/lo
// SC   f32 @ 2,732,288  : 32*4096       (524,288 B)
// BF   f32 @ 3,256,576  : 32*4*4096     (2,097,152 B)
// A2C  f32 @ 5,353,728  : 8*64*128*128  (33,554,432 B)  [per-chunk]
// A3P  u32 @ 38,908,160 : 8*128*64*64   (16,777,216 B)  [per-chunk, packed bf16 hi|lo<<16]

// ---------------- prep: BN-fold + backbone weight transpose ----------------
__global__ __launch_bounds__(256) void prep_k(
    const float* __restrict__ w1, const float* __restrict__ b1, const float* __restrict__ g1,
    const float* __restrict__ be1, const float* __restrict__ m1, const float* __restrict__ v1,
    const float* __restrict__ w2, const float* __restrict__ b2, const float* __restrict__ g2,
    const float* __restrict__ be2, const float* __restrict__ m2, const float* __restrict__ v2,
    const float* __restrict__ w3, const float* __restrict__ b3, const float* __restrict__ g3,
    const float* __restrict__ be3, const float* __restrict__ m3, const float* __restrict__ v3,
    float* __restrict__ W)
{
    int i = blockIdx.x * 256 + threadIdx.x;
    if (i < 864) {                                   // wT1[(kk*3+ci)*32+co]
        int co = i & 31; int r = i >> 5; int ci = r % 3; int kk = r / 3;
        float A = g1[co] * rsqrtf(v1[co] + EPSBN);
        W[i] = w1[(co*3 + ci)*9 + kk] * A;
    } else if (i < 896) {                            // b1 fold
        int co = i - 864;
        float A = g1[co] * rsqrtf(v1[co] + EPSBN);
        W[i] = (b1[co] - m1[co]) * A + be1[co];
    } else if (i < 19328) {                          // wT2[(kk*32+ci)*64+co]
        int j = i - 896; int co = j & 63; int r = j >> 6; int ci = r & 31; int kk = r >> 5;
        float A = g2[co] * rsqrtf(v2[co] + EPSBN);
        W[i] = w2[(co*32 + ci)*9 + kk] * A;
    } else if (i < 19392) {                          // b2 fold
        int co = i - 19328;
        float A = g2[co] * rsqrtf(v2[co] + EPSBN);
        W[i] = (b2[co] - m2[co]) * A + be2[co];
    } else if (i < 93120) {                          // wT3[(kk*64+ci)*128+co]
        int j = i - 19392; int co = j & 127; int r = j >> 7; int ci = r & 63; int kk = r >> 6;
        float A = g3[co] * rsqrtf(v3[co] + EPSBN);
        W[i] = w3[(co*64 + ci)*9 + kk] * A;
    } else if (i < 93248) {                          // b3 fold
        int co = i - 93120;
        float A = g3[co] * rsqrtf(v3[co] + EPSBN);
        W[i] = (b3[co] - m3[co]) * A + be3[co];
    }
}

// ---------------- prep2: head weights -> hi/lo bf16, MFMA-fragment-lane order -------
// WF[head][kk][cig][plane][nf][lane][j]; k = cig*32 + (lane>>4)*8 + j; co = (lane&15)+nf*16
__global__ __launch_bounds__(256) void prep2_k(
    const float* __restrict__ dw1, const float* __restrict__ bw1,
    unsigned short* __restrict__ WF)
{
    int i = blockIdx.x * 256 + threadIdx.x;
    if (i >= 1179648) return;
    int head = i / 589824;
    int r    = i - head * 589824;
    int kk   = r >> 16;
    int r2   = r & 65535;
    int cig  = r2 >> 14;
    int pl   = (r2 >> 13) & 1;
    int nf   = (r2 >> 9) & 15;
    int lane = (r2 >> 3) & 63;
    int j    = r2 & 7;
    int ci = cig*32 + (lane >> 4)*8 + j;
    int co = (lane & 15) + nf*16;
    const float* src = head ? bw1 : dw1;
    float w = src[(co*128 + ci)*9 + kk];
    unsigned short h = f2bf(w);
    WF[i] = pl ? f2bf(w - bf2f(h)) : h;
}

// ---------------- fused conv1(3->32,s2)+BN+ReLU -> conv2(32->64,s2)+BN+ReLU ----------
__global__ __launch_bounds__(256) void conv12_k(
    const float* __restrict__ x, const float* __restrict__ W,
    float* __restrict__ out2, int b0)
{
    __shared__ float s1[17424];                     // 16 * 33 * 33 floats
    const int tid  = threadIdx.x;
    const int lane = tid & 63;
    const int wv   = tid >> 6;
    const int cob  = wv * 16;

    const int bl   = blockIdx.x >> 6;               // chunk-local image 0..7
    const int tile = blockIdx.x & 63;
    const int OY = (tile >> 3) * 16, OX = (tile & 7) * 16;
    const int base1y = 2*OY - 1, base1x = 2*OX - 1;

    const float* xb = x + (size_t)(b0 + bl) * 3 * 262144;

    float acc[4][16];
    #pragma unroll
    for (int j = 0; j < 4; j++)
        #pragma unroll
        for (int c = 0; c < 16; c++) acc[j][c] = 0.f;

    int px[4], py[4];
    #pragma unroll
    for (int j = 0; j < 4; j++) { int p = lane + 64*j; px[j] = p & 15; py[j] = p >> 4; }

    for (int g = 0; g < 2; g++) {
        if (g) __syncthreads();
        for (int idx = tid; idx < 1089; idx += 256) {
            int row = idx / 33;
            int lx  = idx - row*33;
            int y1 = base1y + row;
            int x1 = base1x + lx;
            float c1[16];
            #pragma unroll
            for (int c = 0; c < 16; c++) c1[c] = 0.f;
            if (((unsigned)y1 < 256u) && ((unsigned)x1 < 256u)) {
                #pragma unroll
                for (int ky = 0; ky < 3; ky++) {
                    int xy = 2*y1 + ky - 1;
                    if ((unsigned)xy < 512u) {
                        #pragma unroll
                        for (int kx = 0; kx < 3; kx++) {
                            int xx = 2*x1 + kx - 1;
                            if ((unsigned)xx < 512u) {
                                int kk = ky*3 + kx;
                                #pragma unroll
                                for (int ci = 0; ci < 3; ci++) {
                                    float v = xb[(size_t)ci*262144 + xy*512 + xx];
                                    const float4* w4 = (const float4*)(W + (kk*3+ci)*32 + 16*g);
                                    float4 wa = w4[0], wb = w4[1], wc = w4[2], wd = w4[3];
                                    c1[0]  = fmaf(v, wa.x, c1[0]);  c1[1]  = fmaf(v, wa.y, c1[1]);
                                    c1[2]  = fmaf(v, wa.z, c1[2]);  c1[3]  = fmaf(v, wa.w, c1[3]);
                                    c1[4]  = fmaf(v, wb.x, c1[4]);  c1[5]  = fmaf(v, wb.y, c1[5]);
                                    c1[6]  = fmaf(v, wb.z, c1[6]);  c1[7]  = fmaf(v, wb.w, c1[7]);
                                    c1[8]  = fmaf(v, wc.x, c1[8]);  c1[9]  = fmaf(v, wc.y, c1[9]);
                                    c1[10] = fmaf(v, wc.z, c1[10]); c1[11] = fmaf(v, wc.w, c1[11]);
                                    c1[12] = fmaf(v, wd.x, c1[12]); c1[13] = fmaf(v, wd.y, c1[13]);
                                    c1[14] = fmaf(v, wd.z, c1[14]); c1[15] = fmaf(v, wd.w, c1[15]);
                                }
                            }
                        }
                    }
                }
                #pragma unroll
                for (int c = 0; c < 16; c++)
                    c1[c] = fmaxf(c1[c] + W[864 + 16*g + c], 0.f);
            }
            int xi = (lx & 1) * 17 + (lx >> 1);     // column interleave
            #pragma unroll
            for (int c = 0; c < 16; c++)
                s1[c*1089 + row*33 + xi] = c1[c];
        }
        __syncthreads();
        for (int ky = 0; ky < 3; ky++) {
            for (int kx = 0; kx < 3; kx++) {
                int kk = ky*3 + kx;
                int xbase = (kx & 1) * 17 + (kx >> 1);
                #pragma unroll 2
                for (int ci = 0; ci < 16; ci++) {
                    int cig = 16*g + ci;
                    const float4* w4 = (const float4*)(W + 896 + (kk*32 + cig)*64 + cob);
                    float4 wa = w4[0], wb = w4[1], wc = w4[2], wd = w4[3];
                    #pragma unroll
                    for (int j = 0; j < 4; j++) {
                        float v = s1[ci*1089 + (2*py[j] + ky)*33 + xbase + px[j]];
                        acc[j][0]  = fmaf(v, wa.x, acc[j][0]);  acc[j][1]  = fmaf(v, wa.y, acc[j][1]);
                        acc[j][2]  = fmaf(v, wa.z, acc[j][2]);  acc[j][3]  = fmaf(v, wa.w, acc[j][3]);
                        acc[j][4]  = fmaf(v, wb.x, acc[j][4]);  acc[j][5]  = fmaf(v, wb.y, acc[j][5]);
                        acc[j][6]  = fmaf(v, wb.z, acc[j][6]);  acc[j][7]  = fmaf(v, wb.w, acc[j][7]);
                        acc[j][8]  = fmaf(v, wc.x, acc[j][8]);  acc[j][9]  = fmaf(v, wc.y, acc[j][9]);
                        acc[j][10] = fmaf(v, wc.z, acc[j][10]); acc[j][11] = fmaf(v, wc.w, acc[j][11]);
                        acc[j][12] = fmaf(v, wd.x, acc[j][12]); acc[j][13] = fmaf(v, wd.y, acc[j][13]);
                        acc[j][14] = fmaf(v, wd.z, acc[j][14]); acc[j][15] = fmaf(v, wd.w, acc[j][15]);
                    }
                }
            }
        }
    }
    #pragma unroll
    for (int c = 0; c < 16; c++) {
        float bs = W[19328 + cob + c];
        #pragma unroll
        for (int j = 0; j < 4; j++) {
            float rv = fmaxf(acc[j][c] + bs, 0.f);
            out2[((size_t)(bl*64 + cob + c)*128 + (OY + py[j]))*128 + OX + px[j]] = rv;
        }
    }
}

// ---------------- conv3: 64->128, k3 s2 + BN + ReLU; emits packed bf16 (hi,lo) ------
__global__ __launch_bounds__(256) void conv3_k(
    const float* __restrict__ in, const float* __restrict__ wT,
    const float* __restrict__ bias, unsigned* __restrict__ out)
{
    const int lane = threadIdx.x & 63;
    const int wv   = threadIdx.x >> 6;
    const int cob  = blockIdx.y * 64 + wv * 16;
    const int pix0 = blockIdx.x * 256;              // chunk-local: 8 img * 4096 px
    const int bl   = pix0 >> 12;
    const int off0 = pix0 & 4095;

    float acc[4][16];
    #pragma unroll
    for (int j = 0; j < 4; j++)
        #pragma unroll
        for (int c = 0; c < 16; c++) acc[j][c] = 0.f;

    int oy[4], ox[4];
    #pragma unroll
    for (int j = 0; j < 4; j++) {
        int off = off0 + lane + 64*j;
        ox[j] = off & 63;
        oy[j] = off >> 6;
    }
    const float* inb = in + (size_t)bl * 64 * 16384;

    for (int ky = 0; ky < 3; ky++) {
        for (int kx = 0; kx < 3; kx++) {
            int addr[4]; float mk[4];
            #pragma unroll
            for (int j = 0; j < 4; j++) {
                int iy = oy[j]*2 + ky - 1;
                int ix = ox[j]*2 + kx - 1;
                bool v = ((unsigned)iy < 128u) && ((unsigned)ix < 128u);
                addr[j] = v ? iy*128 + ix : 0;
                mk[j]   = v ? 1.f : 0.f;
            }
            const float* wp = wT + (size_t)((ky*3 + kx)*64)*128 + cob;
            #pragma unroll 2
            for (int ci = 0; ci < 64; ci++) {
                float v0 = inb[(size_t)ci*16384 + addr[0]] * mk[0];
                float v1 = inb[(size_t)ci*16384 + addr[1]] * mk[1];
                float v2 = inb[(size_t)ci*16384 + addr[2]] * mk[2];
                float v3 = inb[(size_t)ci*16384 + addr[3]] * mk[3];
                const float4* w4 = (const float4*)(wp + (size_t)ci*128);
                float4 wa = w4[0], wb = w4[1], wc = w4[2], wd = w4[3];
                float vv[4] = {v0, v1, v2, v3};
                #pragma unroll
                for (int j = 0; j < 4; j++) {
                    float v = vv[j];
                    acc[j][0]  = fmaf(v, wa.x, acc[j][0]);  acc[j][1]  = fmaf(v, wa.y, acc[j][1]);
                    acc[j][2]  = fmaf(v, wa.z, acc[j][2]);  acc[j][3]  = fmaf(v, wa.w, acc[j][3]);
                    acc[j][4]  = fmaf(v, wb.x, acc[j][4]);  acc[j][5]  = fmaf(v, wb.y, acc[j][5]);
                    acc[j][6]  = fmaf(v, wb.z, acc[j][6]);  acc[j][7]  = fmaf(v, wb.w, acc[j][7]);
                    acc[j][8]  = fmaf(v, wc.x, acc[j][8]);  acc[j][9]  = fmaf(v, wc.y, acc[j][9]);
                    acc[j][10] = fmaf(v, wc.z, acc[j][10]); acc[j][11] = fmaf(v, wc.w, acc[j][11]);
                    acc[j][12] = fmaf(v, wd.x, acc[j][12]); acc[j][13] = fmaf(v, wd.y, acc[j][13]);
                    acc[j][14] = fmaf(v, wd.z, acc[j][14]); acc[j][15] = fmaf(v, wd.w, acc[j][15]);
                }
            }
        }
    }
    #pragma unroll
    for (int c = 0; c < 16; c++) {
        float bs = bias[cob + c];
        #pragma unroll
        for (int j = 0; j < 4; j++) {
            float rv = fmaxf(acc[j][c] + bs, 0.f);
            unsigned short h = f2bf(rv);
            unsigned short l = f2bf(rv - bf2f(h));
            out[((size_t)(bl*128 + cob + c))*4096 + off0 + lane + 64*j]
                = (unsigned)h | ((unsigned)l << 16);
        }
    }
}

// ---------------- MFMA head: conv3x3(128->256)+bias+ReLU + 1x1(256->NOUT) ----------
// split-bf16 (hi/lo): acc += ah*bh + ah*bl + al*bh   (f32 MFMA accumulate)
// block: 4 waves, tile M=128px (2 rows) x N=256co; grid (8img*32rp, 2 heads)
__global__ __launch_bounds__(256, 2) void headmm_k(
    const unsigned* __restrict__ A3P, const unsigned short* __restrict__ WF,
    const float* __restrict__ db1, const float* __restrict__ dw2, const float* __restrict__ db2,
    const float* __restrict__ bb1, const float* __restrict__ bw2, const float* __restrict__ bb2,
    float* __restrict__ SC, float* __restrict__ BF, int b0)
{
    __shared__ unsigned short Ah[8704];   // [4 row][68 x'][4 kgrp][8 ci]
    __shared__ unsigned short Al[8704];
    __shared__ float red[2][4][128];

    const int tid  = threadIdx.x;
    const int lane = tid & 63;
    const int w    = tid >> 6;
    const int whi  = w >> 1;                        // row half (0/1)
    const int wco  = w & 1;                         // co half (0/1)
    const int head = blockIdx.y;
    const int imgl = blockIdx.x >> 5;               // chunk-local image
    const int y0   = (blockIdx.x & 31) * 2;         // first of 2 output rows

    f32x4 acc[4][8];
    #pragma unroll
    for (int mf = 0; mf < 4; mf++)
        #pragma unroll
        for (int nf = 0; nf < 8; nf++) {
            f32x4 z = {0.f, 0.f, 0.f, 0.f};
            acc[mf][nf] = z;
        }

    const size_t abase = (size_t)imgl * 128 * 4096;
    const unsigned short* WFh = WF + head * 589824;

    for (int cig = 0; cig < 4; cig++) {
        __syncthreads();                            // prior cig's LDS reads done
        // ---- stage A (4 rows x 66 x' x 32 ci), unpack hi/lo, transposed layout ----
        #pragma unroll 1
        for (int it = 0; it < 33; it++) {
            int f  = tid + it * 256;                // ((row*32+ci)*66 + xi)
            int xi = f % 66;
            int rc = f / 66;
            int ci = rc & 31;
            int row = rc >> 5;
            int gr = y0 + row - 1, gx = xi - 1;
            unsigned val = 0u;
            if (((unsigned)gr < 64u) && ((unsigned)gx < 64u))
                val = A3P[abase + (size_t)(cig*32 + ci)*4096 + gr*64 + gx];
            int a = ((row*68 + xi)*4 + (ci >> 3))*8 + (ci & 7);
            Ah[a] = (unsigned short)(val & 0xffffu);
            Al[a] = (unsigned short)(val >> 16);
        }
        __syncthreads();
        // ---- 9 taps over this 32-ci K-chunk ----
        #pragma unroll 1
        for (int kk = 0; kk < 9; kk++) {
            int ky = kk / 3, kx = kk - 3*(kk/3);
            s16x8 ah[4], al[4];
            #pragma unroll
            for (int mf = 0; mf < 4; mf++) {
                int xq = (lane & 15) + 16*mf + kx;
                int a = (((whi + ky)*68 + xq)*4 + (lane >> 4))*8;
                ah[mf] = *(const s16x8*)&Ah[a];
                al[mf] = *(const s16x8*)&Al[a];
            }
            const unsigned short* wk = WFh + kk*65536 + cig*16384;
            #pragma unroll
            for (int nf = 0; nf < 8; nf++) {
                int nfg = wco*8 + nf;
                s16x8 bh = *(const s16x8*)(wk + nfg*512 + lane*8);
                s16x8 bl = *(const s16x8*)(wk + 8192 + nfg*512 + lane*8);
                #pragma unroll
                for (int mf = 0; mf < 4; mf++) {
                    acc[mf][nf] = __builtin_amdgcn_mfma_f32_16x16x32_bf16(ah[mf], bh, acc[mf][nf], 0, 0, 0);
                    acc[mf][nf] = __builtin_amdgcn_mfma_f32_16x16x32_bf16(ah[mf], bl, acc[mf][nf], 0, 0, 0);
                    acc[mf][nf] = __builtin_amdgcn_mfma_f32_16x16x32_bf16(al[mf], bh, acc[mf][nf], 0, 0, 0);
                }
            }
        }
    }

    // ---- epilogue: +bias, ReLU, then 1x1 (f32 shuffle reduction over co) ----
    const float* b1p = head ? bb1 : db1;
    const float* w2p = head ? bw2 : dw2;
    const float* b2p = head ? bb2 : db2;
    const int NOUT = head ? 4 : 1;

    #pragma unroll
    for (int nf = 0; nf < 8; nf++) {
        float bv = b1p[(lane & 15) + (wco*8 + nf)*16];
        #pragma unroll
        for (int mf = 0; mf < 4; mf++)
            #pragma unroll
            for (int r = 0; r < 4; r++)
                acc[mf][nf][r] = fmaxf(acc[mf][nf][r] + bv, 0.f);
    }

    for (int p = 0; p < NOUT; p++) {
        float part[4][4];
        #pragma unroll
        for (int mf = 0; mf < 4; mf++)
            #pragma unroll
            for (int r = 0; r < 4; r++) part[mf][r] = 0.f;
        #pragma unroll
        for (int nf = 0; nf < 8; nf++) {
            float wq = w2p[p*256 + (lane & 15) + (wco*8 + nf)*16];
            #pragma unroll
            for (int mf = 0; mf < 4; mf++)
                #pragma unroll
                for (int r = 0; r < 4; r++)
                    part[mf][r] = fmaf(acc[mf][nf][r], wq, part[mf][r]);
        }
        #pragma unroll
        for (int mf = 0; mf < 4; mf++)
            #pragma unroll
            for (int r = 0; r < 4; r++) {
                float v = part[mf][r];
                v += __shfl_xor(v, 1);
                v += __shfl_xor(v, 2);
                v += __shfl_xor(v, 4);
                v += __shfl_xor(v, 8);
                if ((lane & 15) == 0)
                    red[wco][p][whi*64 + mf*16 + (lane >> 4)*4 + r] = v;
            }
    }
    __syncthreads();
    float* outp = head ? BF : SC;
    for (int o = tid; o < NOUT*128; o += 256) {
        int p = o >> 7; int px = o & 127;
        float v = red[0][p][px] + red[1][p][px] + b2p[p];
        outp[((size_t)((b0 + imgl)*NOUT + p))*4096 + y0*64 + px] = v;  // raw logit
    }
}

// ---------------- top-8 per image + gather + sigmoid*512 + mask --------------------
__global__ __launch_bounds__(256) void topk_k(
    const float* __restrict__ scores, const float* __restrict__ bflat,
    float* __restrict__ outp)
{
    __shared__ float sv[4096];
    __shared__ float rv[256];
    __shared__ int   ri[256];
    __shared__ float kv[8];
    __shared__ int   kidx[8];
    int b = blockIdx.x, t = threadIdx.x;
    for (int i = t; i < 4096; i += 256) sv[i] = scores[b*4096 + i];
    __syncthreads();
    for (int k = 0; k < 8; k++) {
        float bv = -INFINITY; int bi = 0x7fffffff;
        for (int i = t; i < 4096; i += 256) {
            float v = sv[i];
            if (v > bv || (v == bv && i < bi)) { bv = v; bi = i; }
        }
        rv[t] = bv; ri[t] = bi;
        __syncthreads();
        for (int s = 128; s > 0; s >>= 1) {
            if (t < s) {
                float v2 = rv[t+s]; int i2 = ri[t+s];
                if (v2 > rv[t] || (v2 == rv[t] && i2 < ri[t])) { rv[t] = v2; ri[t] = i2; }
            }
            __syncthreads();
        }
        if (t == 0) { kv[k] = rv[0]; kidx[k] = ri[0]; sv[ri[0]] = -INFINITY; }
        __syncthreads();
    }
    if (t < 32) {
        int k = t >> 2, c = t & 3;
        int idx = kidx[k];
        float s  = 1.f / (1.f + expf(-kv[k]));
        float lg = bflat[((size_t)(b*4 + c))*4096 + idx];
        float box = 512.f / (1.f + expf(-lg));
        outp[(b*8 + k)*4 + c] = (s > 0.5f) ? box : 0.f;
    }
}

extern "C" void kernel_launch(void* const* d_in, const int* in_sizes, int n_in,
                              void* d_out, int out_size, void* d_ws, size_t ws_size,
                              hipStream_t stream)
{
    const float* x   = (const float*)d_in[0];
    const float* w1  = (const float*)d_in[1];
    const float* b1  = (const float*)d_in[2];
    const float* g1  = (const float*)d_in[3];
    const float* be1 = (const float*)d_in[4];
    const float* m1  = (const float*)d_in[5];
    const float* v1  = (const float*)d_in[6];
    const float* w2  = (const float*)d_in[7];
    const float* b2  = (const float*)d_in[8];
    const float* g2  = (const float*)d_in[9];
    const float* be2 = (const float*)d_in[10];
    const float* m2  = (const float*)d_in[11];
    const float* v2  = (const float*)d_in[12];
    const float* w3  = (const float*)d_in[13];
    const float* b3  = (const float*)d_in[14];
    const float* g3  = (const float*)d_in[15];
    const float* be3 = (const float*)d_in[16];
    const float* m3  = (const float*)d_in[17];
    const float* v3  = (const float*)d_in[18];
    const float* dw1 = (const float*)d_in[19];
    const float* db1 = (const float*)d_in[20];
    const float* dw2 = (const float*)d_in[21];
    const float* db2 = (const float*)d_in[22];
    const float* bw1 = (const float*)d_in[23];
    const float* bb1 = (const float*)d_in[24];
    const float* bw2 = (const float*)d_in[25];
    const float* bb2 = (const float*)d_in[26];

    char*  wsb = (char*)d_ws;
    float*          W   = (float*)wsb;
    unsigned short* WF  = (unsigned short*)(wsb + 372992);
    float*          SC  = (float*)(wsb + 2732288);
    float*          BF  = (float*)(wsb + 3256576);
    float*          A2C = (float*)(wsb + 5353728);
    unsigned*       A3P = (unsigned*)(wsb + 38908160);
    float* out = (float*)d_out;

    // prep: backbone BN-fold (93,248 floats) + head weight frag-split (1,179,648 shorts)
    prep_k <<<365, 256, 0, stream>>>(w1,b1,g1,be1,m1,v1, w2,b2,g2,be2,m2,v2,
                                     w3,b3,g3,be3,m3,v3, W);
    prep2_k<<<4608, 256, 0, stream>>>(dw1, bw1, WF);

    // full pipeline in 4 chunks of 8 images (A2C, A3P reused per chunk)
    for (int c = 0; c < 4; c++) {
        conv12_k<<<512, 256, 0, stream>>>(x, W, A2C, c*8);
        conv3_k<<<dim3(128, 2), 256, 0, stream>>>(A2C, W + 19392, W + 93120, A3P);
        headmm_k<<<dim3(256, 2), 256, 0, stream>>>(A3P, WF, db1, dw2, db2, bb1, bw2, bb2,
                                                   SC, BF, c*8);
    }
    // fused top-k + gather + sigmoid + mask
    topk_k<<<32, 256, 0, stream>>>(SC, BF, out);
}

// Round 5
// 1068.744 us; speedup vs baseline: 9.7383x; 2.1684x over previous
//
#include <hip/hip_runtime.h>
#include <math.h>

#define EPSBN 1e-5f

typedef __attribute__((ext_vector_type(4))) float f32x4;
typedef __attribute__((ext_vector_type(8))) short s16x8;

__device__ __forceinline__ unsigned short f2bf(float f) {
    unsigned u = __builtin_bit_cast(unsigned, f);
    u = (u + 0x7fffu + ((u >> 16) & 1u)) >> 16;
    return (unsigned short)u;
}
__device__ __forceinline__ float bf2f(unsigned short s) {
    unsigned u = ((unsigned)s) << 16;
    return __builtin_bit_cast(float, u);
}

// ---------------- workspace layout (BYTE offsets), peak 55,980,288 B ----------------
// W    f32  @ 0          : 93,248 floats (372,992 B)    backbone folded weights
// WF   bf16 @ 372,992    : 1,179,648 shorts (2,359,296 B) head weights, frag hi/lo
// W3F  bf16 @ 2,732,288  : 147,456 shorts (294,912 B)   conv3 weights, frag hi/lo
// SC   f32  @ 3,027,200  : 32*4096   (524,288 B)
// BF   f32  @ 3,551,488  : 32*4*4096 (2,097,152 B)
// A2H  bf16 @ 5,648,640  : 8*128*128*64 shorts (16,777,216 B)  [per-chunk, NHWC hi]
// A2L  bf16 @ 22,425,856 : same (16,777,216 B)                 [per-chunk, NHWC lo]
// A3P  u32  @ 39,203,072 : 8*128*64*64 (16,777,216 B)   [per-chunk, packed hi|lo<<16]

// ---------------- prep: BN-fold + backbone weight transpose ----------------
__global__ __launch_bounds__(256) void prep_k(
    const float* __restrict__ w1, const float* __restrict__ b1, const float* __restrict__ g1,
    const float* __restrict__ be1, const float* __restrict__ m1, const float* __restrict__ v1,
    const float* __restrict__ w2, const float* __restrict__ b2, const float* __restrict__ g2,
    const float* __restrict__ be2, const float* __restrict__ m2, const float* __restrict__ v2,
    const float* __restrict__ w3, const float* __restrict__ b3, const float* __restrict__ g3,
    const float* __restrict__ be3, const float* __restrict__ m3, const float* __restrict__ v3,
    float* __restrict__ W)
{
    int i = blockIdx.x * 256 + threadIdx.x;
    if (i < 864) {                                   // wT1[(kk*3+ci)*32+co]
        int co = i & 31; int r = i >> 5; int ci = r % 3; int kk = r / 3;
        float A = g1[co] * rsqrtf(v1[co] + EPSBN);
        W[i] = w1[(co*3 + ci)*9 + kk] * A;
    } else if (i < 896) {                            // b1 fold
        int co = i - 864;
        float A = g1[co] * rsqrtf(v1[co] + EPSBN);
        W[i] = (b1[co] - m1[co]) * A + be1[co];
    } else if (i < 19328) {                          // wT2[(kk*32+ci)*64+co]
        int j = i - 896; int co = j & 63; int r = j >> 6; int ci = r & 31; int kk = r >> 5;
        float A = g2[co] * rsqrtf(v2[co] + EPSBN);
        W[i] = w2[(co*32 + ci)*9 + kk] * A;
    } else if (i < 19392) {                          // b2 fold
        int co = i - 19328;
        float A = g2[co] * rsqrtf(v2[co] + EPSBN);
        W[i] = (b2[co] - m2[co]) * A + be2[co];
    } else if (i >= 93120 && i < 93248) {            // b3 fold
        int co = i - 93120;
        float A = g3[co] * rsqrtf(v3[co] + EPSBN);
        W[i] = (b3[co] - m3[co]) * A + be3[co];
    }
}

// ---------------- prep2: head weights -> hi/lo bf16, MFMA-fragment-lane order -------
// WF[head][kk][cig][plane][nf][lane][j]; k = cig*32 + (lane>>4)*8 + j; co = (lane&15)+nf*16
__global__ __launch_bounds__(256) void prep2_k(
    const float* __restrict__ dw1, const float* __restrict__ bw1,
    unsigned short* __restrict__ WF)
{
    int i = blockIdx.x * 256 + threadIdx.x;
    if (i >= 1179648) return;
    int head = i / 589824;
    int r    = i - head * 589824;
    int kk   = r >> 16;
    int r2   = r & 65535;
    int cig  = r2 >> 14;
    int pl   = (r2 >> 13) & 1;
    int nf   = (r2 >> 9) & 15;
    int lane = (r2 >> 3) & 63;
    int j    = r2 & 7;
    int ci = cig*32 + (lane >> 4)*8 + j;
    int co = (lane & 15) + nf*16;
    const float* src = head ? bw1 : dw1;
    float w = src[(co*128 + ci)*9 + kk];
    unsigned short h = f2bf(w);
    WF[i] = pl ? f2bf(w - bf2f(h)) : h;
}

// ---------------- prep3: conv3 weights (BN-folded) -> hi/lo bf16, frag order --------
// W3F[(kk*2+cig)*8192 + pl*4096 + nf*512 + lane*8 + j]
// ci = cig*32 + (lane>>4)*8 + j (of 64); co = nf*16 + (lane&15) (of 128)
__global__ __launch_bounds__(256) void prep3_k(
    const float* __restrict__ w3, const float* __restrict__ g3, const float* __restrict__ v3,
    unsigned short* __restrict__ W3F)
{
    int i = blockIdx.x * 256 + threadIdx.x;
    if (i >= 147456) return;
    int kk = i >> 14;
    int r  = i & 16383;
    int cig = r >> 13;
    int pl  = (r >> 12) & 1;
    int nf  = (r >> 9) & 7;
    int lane = (r >> 3) & 63;
    int j   = r & 7;
    int ci = cig*32 + (lane >> 4)*8 + j;
    int co = nf*16 + (lane & 15);
    float A = g3[co] * rsqrtf(v3[co] + EPSBN);
    float w = w3[(co*64 + ci)*9 + kk] * A;
    unsigned short h = f2bf(w);
    W3F[i] = pl ? f2bf(w - bf2f(h)) : h;
}

// ---------------- fused conv1(3->32,s2)+BN+ReLU -> conv2(32->64,s2)+BN+ReLU ----------
// emits A2 as NHWC bf16 hi/lo planes: A2H/A2L[(bl*16384 + y*128 + x)*64 + ci]
__global__ __launch_bounds__(256) void conv12_k(
    const float* __restrict__ x, const float* __restrict__ W,
    unsigned short* __restrict__ A2H, unsigned short* __restrict__ A2L, int b0)
{
    __shared__ float s1[17424];                     // 16 * 33 * 33 floats
    const int tid  = threadIdx.x;
    const int lane = tid & 63;
    const int wv   = tid >> 6;
    const int cob  = wv * 16;

    const int bl   = blockIdx.x >> 6;               // chunk-local image 0..7
    const int tile = blockIdx.x & 63;
    const int OY = (tile >> 3) * 16, OX = (tile & 7) * 16;
    const int base1y = 2*OY - 1, base1x = 2*OX - 1;

    const float* xb = x + (size_t)(b0 + bl) * 3 * 262144;

    float acc[4][16];
    #pragma unroll
    for (int j = 0; j < 4; j++)
        #pragma unroll
        for (int c = 0; c < 16; c++) acc[j][c] = 0.f;

    int px[4], py[4];
    #pragma unroll
    for (int j = 0; j < 4; j++) { int p = lane + 64*j; px[j] = p & 15; py[j] = p >> 4; }

    for (int g = 0; g < 2; g++) {
        if (g) __syncthreads();
        for (int idx = tid; idx < 1089; idx += 256) {
            int row = idx / 33;
            int lx  = idx - row*33;
            int y1 = base1y + row;
            int x1 = base1x + lx;
            float c1[16];
            #pragma unroll
            for (int c = 0; c < 16; c++) c1[c] = 0.f;
            if (((unsigned)y1 < 256u) && ((unsigned)x1 < 256u)) {
                #pragma unroll
                for (int ky = 0; ky < 3; ky++) {
                    int xy = 2*y1 + ky - 1;
                    if ((unsigned)xy < 512u) {
                        #pragma unroll
                        for (int kx = 0; kx < 3; kx++) {
                            int xx = 2*x1 + kx - 1;
                            if ((unsigned)xx < 512u) {
                                int kk = ky*3 + kx;
                                #pragma unroll
                                for (int ci = 0; ci < 3; ci++) {
                                    float v = xb[(size_t)ci*262144 + xy*512 + xx];
                                    const float4* w4 = (const float4*)(W + (kk*3+ci)*32 + 16*g);
                                    float4 wa = w4[0], wb = w4[1], wc = w4[2], wd = w4[3];
                                    c1[0]  = fmaf(v, wa.x, c1[0]);  c1[1]  = fmaf(v, wa.y, c1[1]);
                                    c1[2]  = fmaf(v, wa.z, c1[2]);  c1[3]  = fmaf(v, wa.w, c1[3]);
                                    c1[4]  = fmaf(v, wb.x, c1[4]);  c1[5]  = fmaf(v, wb.y, c1[5]);
                                    c1[6]  = fmaf(v, wb.z, c1[6]);  c1[7]  = fmaf(v, wb.w, c1[7]);
                                    c1[8]  = fmaf(v, wc.x, c1[8]);  c1[9]  = fmaf(v, wc.y, c1[9]);
                                    c1[10] = fmaf(v, wc.z, c1[10]); c1[11] = fmaf(v, wc.w, c1[11]);
                                    c1[12] = fmaf(v, wd.x, c1[12]); c1[13] = fmaf(v, wd.y, c1[13]);
                                    c1[14] = fmaf(v, wd.z, c1[14]); c1[15] = fmaf(v, wd.w, c1[15]);
                                }
                            }
                        }
                    }
                }
                #pragma unroll
                for (int c = 0; c < 16; c++)
                    c1[c] = fmaxf(c1[c] + W[864 + 16*g + c], 0.f);
            }
            int xi = (lx & 1) * 17 + (lx >> 1);     // column interleave
            #pragma unroll
            for (int c = 0; c < 16; c++)
                s1[c*1089 + row*33 + xi] = c1[c];
        }
        __syncthreads();
        for (int ky = 0; ky < 3; ky++) {
            for (int kx = 0; kx < 3; kx++) {
                int kk = ky*3 + kx;
                int xbase = (kx & 1) * 17 + (kx >> 1);
                #pragma unroll 2
                for (int ci = 0; ci < 16; ci++) {
                    int cig = 16*g + ci;
                    const float4* w4 = (const float4*)(W + 896 + (kk*32 + cig)*64 + cob);
                    float4 wa = w4[0], wb = w4[1], wc = w4[2], wd = w4[3];
                    #pragma unroll
                    for (int j = 0; j < 4; j++) {
                        float v = s1[ci*1089 + (2*py[j] + ky)*33 + xbase + px[j]];
                        acc[j][0]  = fmaf(v, wa.x, acc[j][0]);  acc[j][1]  = fmaf(v, wa.y, acc[j][1]);
                        acc[j][2]  = fmaf(v, wa.z, acc[j][2]);  acc[j][3]  = fmaf(v, wa.w, acc[j][3]);
                        acc[j][4]  = fmaf(v, wb.x, acc[j][4]);  acc[j][5]  = fmaf(v, wb.y, acc[j][5]);
                        acc[j][6]  = fmaf(v, wb.z, acc[j][6]);  acc[j][7]  = fmaf(v, wb.w, acc[j][7]);
                        acc[j][8]  = fmaf(v, wc.x, acc[j][8]);  acc[j][9]  = fmaf(v, wc.y, acc[j][9]);
                        acc[j][10] = fmaf(v, wc.z, acc[j][10]); acc[j][11] = fmaf(v, wc.w, acc[j][11]);
                        acc[j][12] = fmaf(v, wd.x, acc[j][12]); acc[j][13] = fmaf(v, wd.y, acc[j][13]);
                        acc[j][14] = fmaf(v, wd.z, acc[j][14]); acc[j][15] = fmaf(v, wd.w, acc[j][15]);
                    }
                }
            }
        }
    }
    // epilogue: bias + relu -> bf16 hi/lo NHWC planes (16 ci contiguous per px)
    #pragma unroll
    for (int j = 0; j < 4; j++) {
        unsigned hv[8], lv[8];
        #pragma unroll
        for (int c = 0; c < 8; c++) {
            float r0 = fmaxf(acc[j][2*c]   + W[19328 + cob + 2*c],   0.f);
            float r1 = fmaxf(acc[j][2*c+1] + W[19328 + cob + 2*c+1], 0.f);
            unsigned short h0 = f2bf(r0), h1 = f2bf(r1);
            unsigned short l0 = f2bf(r0 - bf2f(h0)), l1 = f2bf(r1 - bf2f(h1));
            hv[c] = (unsigned)h0 | ((unsigned)h1 << 16);
            lv[c] = (unsigned)l0 | ((unsigned)l1 << 16);
        }
        size_t base = ((size_t)(bl*16384 + (OY + py[j])*128 + OX + px[j]))*64 + cob;
        uint4 th0, th1, tl0, tl1;
        th0.x = hv[0]; th0.y = hv[1]; th0.z = hv[2]; th0.w = hv[3];
        th1.x = hv[4]; th1.y = hv[5]; th1.z = hv[6]; th1.w = hv[7];
        tl0.x = lv[0]; tl0.y = lv[1]; tl0.z = lv[2]; tl0.w = lv[3];
        tl1.x = lv[4]; tl1.y = lv[5]; tl1.z = lv[6]; tl1.w = lv[7];
        ((uint4*)(A2H + base))[0] = th0;
        ((uint4*)(A2H + base))[1] = th1;
        ((uint4*)(A2L + base))[0] = tl0;
        ((uint4*)(A2L + base))[1] = tl1;
    }
}

// ---------------- conv3 MFMA: 64->128, k3 s2, split-bf16, NHWC in -> A3P out --------
// block: 4 waves = 2 rows x 2 co-halves; wave: 64px x 64co (4 mf x 4 nf).
// grid per chunk: 8 img * 32 row-pairs = 256 blocks.
__global__ __launch_bounds__(256, 2) void conv3mm_k(
    const unsigned short* __restrict__ A2H, const unsigned short* __restrict__ A2L,
    const unsigned short* __restrict__ W3F, const float* __restrict__ bias,
    unsigned* __restrict__ A3P)
{
    const int tid  = threadIdx.x;
    const int lane = tid & 63;
    const int w    = tid >> 6;
    const int wm   = w >> 1;                        // row 0/1
    const int wn   = w & 1;                         // co half
    const int bl   = blockIdx.x >> 5;               // chunk-local image
    const int y0   = (blockIdx.x & 31) * 2;
    const int y    = y0 + wm;
    const int m    = lane & 15;
    const int ks   = lane >> 4;

    f32x4 acc[4][4];
    #pragma unroll
    for (int mf = 0; mf < 4; mf++)
        #pragma unroll
        for (int nf = 0; nf < 4; nf++) {
            f32x4 z = {0.f, 0.f, 0.f, 0.f};
            acc[mf][nf] = z;
        }

    const size_t ibase = (size_t)bl * 16384 * 64;

    for (int ky = 0; ky < 3; ky++) {
        int iy = 2*y + ky - 1;
        if ((unsigned)iy >= 128u) continue;         // zero-pad row
        for (int kx = 0; kx < 3; kx++) {
            int kk = ky*3 + kx;
            #pragma unroll
            for (int cig = 0; cig < 2; cig++) {
                s16x8 ah[4], al[4];
                #pragma unroll
                for (int mf = 0; mf < 4; mf++) {
                    int xo = mf*16 + m;
                    int ix = 2*xo + kx - 1;
                    bool v = ix >= 0;               // ix<=127 always
                    int ixc = v ? ix : 0;
                    size_t a = ibase + ((size_t)iy*128 + ixc)*64 + cig*32 + ks*8;
                    s16x8 zh = {0,0,0,0,0,0,0,0};
                    s16x8 th = *(const s16x8*)(A2H + a);
                    s16x8 tl = *(const s16x8*)(A2L + a);
                    ah[mf] = v ? th : zh;
                    al[mf] = v ? tl : zh;
                }
                const unsigned short* wb = W3F + (kk*2 + cig)*8192;
                #pragma unroll
                for (int nf = 0; nf < 4; nf++) {
                    int nfg = wn*4 + nf;
                    s16x8 bh  = *(const s16x8*)(wb + nfg*512 + lane*8);
                    s16x8 blo = *(const s16x8*)(wb + 4096 + nfg*512 + lane*8);
                    #pragma unroll
                    for (int mf = 0; mf < 4; mf++) {
                        acc[mf][nf] = __builtin_amdgcn_mfma_f32_16x16x32_bf16(ah[mf], bh,  acc[mf][nf], 0, 0, 0);
                        acc[mf][nf] = __builtin_amdgcn_mfma_f32_16x16x32_bf16(ah[mf], blo, acc[mf][nf], 0, 0, 0);
                        acc[mf][nf] = __builtin_amdgcn_mfma_f32_16x16x32_bf16(al[mf], bh,  acc[mf][nf], 0, 0, 0);
                    }
                }
            }
        }
    }

    // epilogue: +bias, ReLU, pack hi/lo, write A3P[bl][co][y][x]
    #pragma unroll
    for (int nf = 0; nf < 4; nf++) {
        int co = wn*64 + nf*16 + m;
        float bv = bias[co];
        size_t obase = ((size_t)(bl*128 + co)*64 + y)*64;
        #pragma unroll
        for (int mf = 0; mf < 4; mf++) {
            #pragma unroll
            for (int r = 0; r < 4; r++) {
                float rv = fmaxf(acc[mf][nf][r] + bv, 0.f);
                unsigned short h = f2bf(rv);
                unsigned short l = f2bf(rv - bf2f(h));
                int xo = mf*16 + ks*4 + r;
                A3P[obase + xo] = (unsigned)h | ((unsigned)l << 16);
            }
        }
    }
}

// ---------------- MFMA head: conv3x3(128->256)+bias+ReLU + 1x1(256->NOUT) ----------
__global__ __launch_bounds__(256, 2) void headmm_k(
    const unsigned* __restrict__ A3P, const unsigned short* __restrict__ WF,
    const float* __restrict__ db1, const float* __restrict__ dw2, const float* __restrict__ db2,
    const float* __restrict__ bb1, const float* __restrict__ bw2, const float* __restrict__ bb2,
    float* __restrict__ SC, float* __restrict__ BF, int b0)
{
    __shared__ unsigned short Ah[8704];   // [4 row][68 x'][4 kgrp][8 ci]
    __shared__ unsigned short Al[8704];
    __shared__ float red[2][4][128];

    const int tid  = threadIdx.x;
    const int lane = tid & 63;
    const int w    = tid >> 6;
    const int whi  = w >> 1;                        // row half (0/1)
    const int wco  = w & 1;                         // co half (0/1)
    const int head = blockIdx.y;
    const int imgl = blockIdx.x >> 5;               // chunk-local image
    const int y0   = (blockIdx.x & 31) * 2;         // first of 2 output rows

    f32x4 acc[4][8];
    #pragma unroll
    for (int mf = 0; mf < 4; mf++)
        #pragma unroll
        for (int nf = 0; nf < 8; nf++) {
            f32x4 z = {0.f, 0.f, 0.f, 0.f};
            acc[mf][nf] = z;
        }

    const size_t abase = (size_t)imgl * 128 * 4096;
    const unsigned short* WFh = WF + head * 589824;

    for (int cig = 0; cig < 4; cig++) {
        __syncthreads();
        #pragma unroll 1
        for (int it = 0; it < 33; it++) {
            int f  = tid + it * 256;
            int xi = f % 66;
            int rc = f / 66;
            int ci = rc & 31;
            int row = rc >> 5;
            int gr = y0 + row - 1, gx = xi - 1;
            unsigned val = 0u;
            if (((unsigned)gr < 64u) && ((unsigned)gx < 64u))
                val = A3P[abase + (size_t)(cig*32 + ci)*4096 + gr*64 + gx];
            int a = ((row*68 + xi)*4 + (ci >> 3))*8 + (ci & 7);
            Ah[a] = (unsigned short)(val & 0xffffu);
            Al[a] = (unsigned short)(val >> 16);
        }
        __syncthreads();
        #pragma unroll 1
        for (int kk = 0; kk < 9; kk++) {
            int ky = kk / 3, kx = kk - 3*(kk/3);
            s16x8 ah[4], al[4];
            #pragma unroll
            for (int mf = 0; mf < 4; mf++) {
                int xq = (lane & 15) + 16*mf + kx;
                int a = (((whi + ky)*68 + xq)*4 + (lane >> 4))*8;
                ah[mf] = *(const s16x8*)&Ah[a];
                al[mf] = *(const s16x8*)&Al[a];
            }
            const unsigned short* wk = WFh + kk*65536 + cig*16384;
            #pragma unroll
            for (int nf = 0; nf < 8; nf++) {
                int nfg = wco*8 + nf;
                s16x8 bh = *(const s16x8*)(wk + nfg*512 + lane*8);
                s16x8 bl = *(const s16x8*)(wk + 8192 + nfg*512 + lane*8);
                #pragma unroll
                for (int mf = 0; mf < 4; mf++) {
                    acc[mf][nf] = __builtin_amdgcn_mfma_f32_16x16x32_bf16(ah[mf], bh, acc[mf][nf], 0, 0, 0);
                    acc[mf][nf] = __builtin_amdgcn_mfma_f32_16x16x32_bf16(ah[mf], bl, acc[mf][nf], 0, 0, 0);
                    acc[mf][nf] = __builtin_amdgcn_mfma_f32_16x16x32_bf16(al[mf], bh, acc[mf][nf], 0, 0, 0);
                }
            }
        }
    }

    const float* b1p = head ? bb1 : db1;
    const float* w2p = head ? bw2 : dw2;
    const float* b2p = head ? bb2 : db2;
    const int NOUT = head ? 4 : 1;

    #pragma unroll
    for (int nf = 0; nf < 8; nf++) {
        float bv = b1p[(lane & 15) + (wco*8 + nf)*16];
        #pragma unroll
        for (int mf = 0; mf < 4; mf++)
            #pragma unroll
            for (int r = 0; r < 4; r++)
                acc[mf][nf][r] = fmaxf(acc[mf][nf][r] + bv, 0.f);
    }

    for (int p = 0; p < NOUT; p++) {
        float part[4][4];
        #pragma unroll
        for (int mf = 0; mf < 4; mf++)
            #pragma unroll
            for (int r = 0; r < 4; r++) part[mf][r] = 0.f;
        #pragma unroll
        for (int nf = 0; nf < 8; nf++) {
            float wq = w2p[p*256 + (lane & 15) + (wco*8 + nf)*16];
            #pragma unroll
            for (int mf = 0; mf < 4; mf++)
                #pragma unroll
                for (int r = 0; r < 4; r++)
                    part[mf][r] = fmaf(acc[mf][nf][r], wq, part[mf][r]);
        }
        #pragma unroll
        for (int mf = 0; mf < 4; mf++)
            #pragma unroll
            for (int r = 0; r < 4; r++) {
                float v = part[mf][r];
                v += __shfl_xor(v, 1);
                v += __shfl_xor(v, 2);
                v += __shfl_xor(v, 4);
                v += __shfl_xor(v, 8);
                if ((lane & 15) == 0)
                    red[wco][p][whi*64 + mf*16 + (lane >> 4)*4 + r] = v;
            }
    }
    __syncthreads();
    float* outp = head ? BF : SC;
    for (int o = tid; o < NOUT*128; o += 256) {
        int p = o >> 7; int px = o & 127;
        float v = red[0][p][px] + red[1][p][px] + b2p[p];
        outp[((size_t)((b0 + imgl)*NOUT + p))*4096 + y0*64 + px] = v;
    }
}

// ---------------- top-8 per image + gather + sigmoid*512 + mask --------------------
__global__ __launch_bounds__(256) void topk_k(
    const float* __restrict__ scores, const float* __restrict__ bflat,
    float* __restrict__ outp)
{
    __shared__ float sv[4096];
    __shared__ float rv[256];
    __shared__ int   ri[256];
    __shared__ float kv[8];
    __shared__ int   kidx[8];
    int b = blockIdx.x, t = threadIdx.x;
    for (int i = t; i < 4096; i += 256) sv[i] = scores[b*4096 + i];
    __syncthreads();
    for (int k = 0; k < 8; k++) {
        float bv = -INFINITY; int bi = 0x7fffffff;
        for (int i = t; i < 4096; i += 256) {
            float v = sv[i];
            if (v > bv || (v == bv && i < bi)) { bv = v; bi = i; }
        }
        rv[t] = bv; ri[t] = bi;
        __syncthreads();
        for (int s = 128; s > 0; s >>= 1) {
            if (t < s) {
                float v2 = rv[t+s]; int i2 = ri[t+s];
                if (v2 > rv[t] || (v2 == rv[t] && i2 < ri[t])) { rv[t] = v2; ri[t] = i2; }
            }
            __syncthreads();
        }
        if (t == 0) { kv[k] = rv[0]; kidx[k] = ri[0]; sv[ri[0]] = -INFINITY; }
        __syncthreads();
    }
    if (t < 32) {
        int k = t >> 2, c = t & 3;
        int idx = kidx[k];
        float s  = 1.f / (1.f + expf(-kv[k]));
        float lg = bflat[((size_t)(b*4 + c))*4096 + idx];
        float box = 512.f / (1.f + expf(-lg));
        outp[(b*8 + k)*4 + c] = (s > 0.5f) ? box : 0.f;
    }
}

extern "C" void kernel_launch(void* const* d_in, const int* in_sizes, int n_in,
                              void* d_out, int out_size, void* d_ws, size_t ws_size,
                              hipStream_t stream)
{
    const float* x   = (const float*)d_in[0];
    const float* w1  = (const float*)d_in[1];
    const float* b1  = (const float*)d_in[2];
    const float* g1  = (const float*)d_in[3];
    const float* be1 = (const float*)d_in[4];
    const float* m1  = (const float*)d_in[5];
    const float* v1  = (const float*)d_in[6];
    const float* w2  = (const float*)d_in[7];
    const float* b2  = (const float*)d_in[8];
    const float* g2  = (const float*)d_in[9];
    const float* be2 = (const float*)d_in[10];
    const float* m2  = (const float*)d_in[11];
    const float* v2  = (const float*)d_in[12];
    const float* w3  = (const float*)d_in[13];
    const float* b3  = (const float*)d_in[14];
    const float* g3  = (const float*)d_in[15];
    const float* be3 = (const float*)d_in[16];
    const float* m3  = (const float*)d_in[17];
    const float* v3  = (const float*)d_in[18];
    const float* dw1 = (const float*)d_in[19];
    const float* db1 = (const float*)d_in[20];
    const float* dw2 = (const float*)d_in[21];
    const float* db2 = (const float*)d_in[22];
    const float* bw1 = (const float*)d_in[23];
    const float* bb1 = (const float*)d_in[24];
    const float* bw2 = (const float*)d_in[25];
    const float* bb2 = (const float*)d_in[26];

    char*  wsb = (char*)d_ws;
    float*          W   = (float*)wsb;
    unsigned short* WF  = (unsigned short*)(wsb + 372992);
    unsigned short* W3F = (unsigned short*)(wsb + 2732288);
    float*          SC  = (float*)(wsb + 3027200);
    float*          BF  = (float*)(wsb + 3551488);
    unsigned short* A2H = (unsigned short*)(wsb + 5648640);
    unsigned short* A2L = (unsigned short*)(wsb + 22425856);
    unsigned*       A3P = (unsigned*)(wsb + 39203072);
    float* out = (float*)d_out;

    // prep: backbone fold + head/conv3 weight frag-splits
    prep_k <<<365, 256, 0, stream>>>(w1,b1,g1,be1,m1,v1, w2,b2,g2,be2,m2,v2,
                                     w3,b3,g3,be3,m3,v3, W);
    prep2_k<<<4608, 256, 0, stream>>>(dw1, bw1, WF);
    prep3_k<<<576, 256, 0, stream>>>(w3, g3, v3, W3F);

    // full pipeline in 4 chunks of 8 images (A2H/A2L, A3P reused per chunk)
    for (int c = 0; c < 4; c++) {
        conv12_k <<<512, 256, 0, stream>>>(x, W, A2H, A2L, c*8);
        conv3mm_k<<<256, 256, 0, stream>>>(A2H, A2L, W3F, W + 93120, A3P);
        headmm_k <<<dim3(256, 2), 256, 0, stream>>>(A3P, WF, db1, dw2, db2, bb1, bw2, bb2,
                                                    SC, BF, c*8);
    }
    // fused top-k + gather + sigmoid + mask
    topk_k<<<32, 256, 0, stream>>>(SC, BF, out);
}